// Round 12
// baseline (131.118 us; speedup 1.0000x reference)
//
#include <hip/hip_runtime.h>
#include <math.h>

// Problem constants
#define NB   16
#define NC   64
#define HWs  4096
#define NPS  1024
#define LOG2E 1.44269504088896341f

// ws layout in ushort (bf16 bit patterns)
static constexpr size_t PHI_OFF = (size_t)NB * HWs * 8;            // theta: [b][4096][8]
static constexpr size_t GT_OFF  = PHI_OFF + (size_t)NB * NPS * 8;  // phi:   [b][1024][8]
// gT: [b][32][1024]; total 1,179,648 ushorts = 2.25 MB

typedef short s16x8 __attribute__((ext_vector_type(8)));
typedef float f32x4 __attribute__((ext_vector_type(4)));

#define LD8G(p) (*(const s16x8*)(p))
#define SB()    __builtin_amdgcn_sched_barrier(0)

__device__ inline unsigned short f2bf(float f) {
    unsigned int u = __float_as_uint(f);
    u += 0x7fffu + ((u >> 16) & 1u);          // RNE
    return (unsigned short)(u >> 16);
}
__device__ inline unsigned int pk2(float a, float b) {
    unsigned int ua = __float_as_uint(a); ua += 0x7fffu + ((ua >> 16) & 1u);
    unsigned int ub = __float_as_uint(b); ub += 0x7fffu + ((ub >> 16) & 1u);
    return (ua >> 16) | (ub & 0xffff0000u);
}

// ---------------------------------------------------------------------------
// Kernel 1 (v7): weights staged in LDS — zero SMEM in the inner loop.
// Round-16 post-mortem: v6 readlane regressed (28 -> ~45 us): it swapped
// free scalar-pipe s_loads for 6 extra VALU ops/ci + SGPR-write hazards.
// Reverted. The v4~=v5 invariance is still best explained by lgkm-mixing:
// s_load returns OUT-OF-ORDER on gfx9 -> mixing s_load + ds_read in a loop
// forces full lgkmcnt(0) drains every unroll chunk (~250 cy x 8), blind to
// MAC count and occupancy. v7 keeps v5's shape but stages the block's 24
// weight rows (6 KB) in LDS: loop reads weights as wave-uniform
// ds_read_b128 (broadcast, conflict-free) + x as 2-way b32. DS-only lgkm is
// IN-ORDER -> compiler emits counted lgkmcnt(N), 160 ds ops pipeline across
// the full unroll. Same fp32 math/order/outputs as v5. LDS 22.5 KB -> 7
// blocks/CU. Predict proj ~28 -> 8-12 us (verify via total).
// ---------------------------------------------------------------------------
__global__ __launch_bounds__(256) void k_proj(
    const float* __restrict__ x, const float* __restrict__ Wt,
    const float* __restrict__ Wp, const float* __restrict__ Wg,
    unsigned short* __restrict__ ws)
{
    __shared__ float xs[64 * 64];             // 16 KB
    __shared__ float Wl[24 * 64];             // 6 KB: rows 0-7 = W8, 8-23 = WG

    unsigned short* theta = ws;
    unsigned short* phi   = ws + PHI_OFF;
    unsigned short* gT    = ws + GT_OFF;

    const int tid  = threadIdx.x;
    const int blk  = blockIdx.x;
    const int b    = blk >> 7;
    const int rp   = (blk >> 2) & 31;         // image rows {2rp, 2rp+1}
    const int half = (blk >> 1) & 1;          // block-uniform -> SGPR
    const int csub = blk & 1;                 // column half (32 cols)
    const int col0 = csub * 32;

    // ---- stage weights (coalesced; branch uniform per k) ----
    const float* W8s = half ? Wp : Wt;                  // [8][64]
    const float* WGs = Wg + half * 16 * NC;             // [16][64]
#pragma unroll
    for (int k = 0; k < 6; ++k) {
        const int idx = k * 256 + tid;                  // 0..1535
        Wl[idx] = (idx < 512) ? W8s[idx] : WGs[idx - 512];
    }

    // ---- stage x[b][ci][rows 2rp,2rp+1][cols col0..col0+32) -> xs[ci][64] ----
    const float* xsrc = x + (size_t)b * NC * HWs + rp * 128;
#pragma unroll
    for (int i = 0; i < 4; ++i) {
        const int idx  = i * 256 + tid;       // 0..1023 float4 slots
        const int ci   = idx >> 4;
        const int slot = idx & 15;
        const int r    = slot >> 3;
        const int c4   = slot & 7;
        float4 v = *(const float4*)(xsrc + (size_t)ci * HWs + r * 64 + col0 + c4 * 4);
        *(float4*)(xs + ci * 64 + r * 32 + c4 * 4) = v;
    }
    __syncthreads();

    const int pxl = tid & 63;                 // r = pxl>>5, c = pxl&31
    const int r   = pxl >> 5;
    const int c   = pxl & 31;
    const int grp = __builtin_amdgcn_readfirstlane(tid >> 6);   // 0..3, SGPR

    float a2[2], ag4[4];
#pragma unroll
    for (int j = 0; j < 2; ++j) a2[j] = 0.f;
#pragma unroll
    for (int j = 0; j < 4; ++j) ag4[j] = 0.f;

    // wave-uniform weight row bases (LDS, float4 view)
    const f32x4* w8r0 = (const f32x4*)(Wl + (grp * 2 + 0) * NC);
    const f32x4* w8r1 = (const f32x4*)(Wl + (grp * 2 + 1) * NC);
    const f32x4* wgr0 = (const f32x4*)(Wl + (8 + grp * 4 + 0) * NC);
    const f32x4* wgr1 = (const f32x4*)(Wl + (8 + grp * 4 + 1) * NC);
    const f32x4* wgr2 = (const f32x4*)(Wl + (8 + grp * 4 + 2) * NC);
    const f32x4* wgr3 = (const f32x4*)(Wl + (8 + grp * 4 + 3) * NC);

#pragma unroll
    for (int q4 = 0; q4 < 16; ++q4) {
        const f32x4 w0 = w8r0[q4];            // ds_read_b128, broadcast
        const f32x4 w1 = w8r1[q4];
        const f32x4 g0 = wgr0[q4];
        const f32x4 g1 = wgr1[q4];
        const f32x4 g2 = wgr2[q4];
        const f32x4 g3 = wgr3[q4];
        const float xv0 = xs[(q4 * 4 + 0) * 64 + pxl];
        const float xv1 = xs[(q4 * 4 + 1) * 64 + pxl];
        const float xv2 = xs[(q4 * 4 + 2) * 64 + pxl];
        const float xv3 = xs[(q4 * 4 + 3) * 64 + pxl];
        // sequential fmacs preserve ascending-ci order per accumulator
        a2[0] += w0[0] * xv0; a2[0] += w0[1] * xv1; a2[0] += w0[2] * xv2; a2[0] += w0[3] * xv3;
        a2[1] += w1[0] * xv0; a2[1] += w1[1] * xv1; a2[1] += w1[2] * xv2; a2[1] += w1[3] * xv3;
        ag4[0] += g0[0] * xv0; ag4[0] += g0[1] * xv1; ag4[0] += g0[2] * xv2; ag4[0] += g0[3] * xv3;
        ag4[1] += g1[0] * xv0; ag4[1] += g1[1] * xv1; ag4[1] += g1[2] * xv2; ag4[1] += g1[3] * xv3;
        ag4[2] += g2[0] * xv0; ag4[2] += g2[1] * xv1; ag4[2] += g2[2] * xv2; ag4[2] += g2[3] * xv3;
        ag4[3] += g3[0] * xv0; ag4[3] += g3[1] * xv1; ag4[3] += g3[2] * xv2; ag4[3] += g3[3] * xv3;
    }

    if (half == 0) {
        // theta: unpooled, scaled by log2e; channels grp*2 .. grp*2+2
        const int q = (2 * rp + r) * 64 + col0 + c;
        *(unsigned int*)(theta + ((size_t)b * HWs + q) * 8 + grp * 2) =
            pk2(a2[0] * LOG2E, a2[1] * LOG2E);
    } else {
        // phi pooling: row pair (xor 32), col pair (xor 1)
#pragma unroll
        for (int j = 0; j < 2; ++j) {
            float v = a2[j];
            v = fmaxf(v, __shfl_xor(v, 32));
            v = fmaxf(v, __shfl_xor(v, 1));
            a2[j] = v;
        }
    }

    // g pooling (both halves)
#pragma unroll
    for (int j = 0; j < 4; ++j) {
        float v = ag4[j];
        v = fmaxf(v, __shfl_xor(v, 32));
        v = fmaxf(v, __shfl_xor(v, 1));
        ag4[j] = v;
    }

    if (r == 0 && (c & 1) == 0) {
        const int ps = rp * 32 + csub * 16 + (c >> 1);
        if (half == 1) {
            *(unsigned int*)(phi + ((size_t)b * NPS + ps) * 8 + grp * 2) =
                pk2(a2[0], a2[1]);
        }
#pragma unroll
        for (int j = 0; j < 4; ++j) {
            const int ch = half * 16 + grp * 4 + j;
            gT[((size_t)b * 32 + ch) * NPS + ps] = f2bf(ag4[j]);
        }
    }
}

// ---------------------------------------------------------------------------
// Kernel 2 (v11): L2-dedup + tile stagger. UNCHANGED (one variable per
// round; v11 landed 48 -> ~34 us, confirmed by totals).
// (1) G-tile (4 KB) staged ONCE per block via asm loads + XOR-swizzled
// ds_write; PV reads frags via swizzled ds_read_b128. One __syncthreads per
// tile = the cross-wave hand-off. (2) Stagger tile order st=(t+blk&15)&15 —
// legal: non-online softmax, tile order is permutation-invariant.
// vmcnt ledger: 5 loads/body; vmcnt(4) before ds_write, vmcnt(5) before QK,
// body-15 waits 0. LDS: P 18432 + stage 8192 = 26624 B.
// ---------------------------------------------------------------------------
__global__ __launch_bounds__(256) __attribute__((amdgpu_waves_per_eu(4, 4)))
void k_attn(
    const float* __restrict__ x, const float* __restrict__ Wo,
    const float* __restrict__ gamma_p, const unsigned short* __restrict__ ws,
    float* __restrict__ out)
{
    __shared__ __align__(16) unsigned char smem[26624];

    const int tid  = threadIdx.x;
    const int wave = __builtin_amdgcn_readfirstlane(tid >> 6);
    const int lane = tid & 63;
    const int quad = lane >> 4, lr = lane & 15;
    const int blk  = blockIdx.x;
    const int b    = blk >> 6;
    const int q0   = (blk & 63) * 64;
    const int stoff = blk & 15;               // tile stagger (block-uniform)

    const unsigned short* th = ws + (size_t)b * HWs * 8;
    const unsigned short* ph = ws + PHI_OFF + (size_t)b * NPS * 8;
    const unsigned short* gp = ws + GT_OFF + (size_t)b * 32 * NPS;
    unsigned short* Pw  = (unsigned short*)smem + wave * 2304;     // 2 bufs x [16 q][72 s]
    unsigned short* stg = (unsigned short*)(smem + 18432);         // 2 bufs x [32 ch][64 s]

    // G staging map: thread -> one 16B chunk (ch = tid>>3, part = tid&7),
    // XOR-swizzled column so frag reads spread across banks.
    const int sch   = tid >> 3;
    const int spart = tid & 7;
    const int swz   = spart ^ (sch & 7);
    const int voff_gc = sch * (NPS * 2) + spart * 16;   // byte voffset into gT slab

    const s16x8 zf = {0, 0, 0, 0, 0, 0, 0, 0};
    const f32x4 zc = {0.f, 0.f, 0.f, 0.f};

    // theta A-fragment: A[m=q=lr][k=quad*8+j], real k<8 in quad 0
    const s16x8 thA = (quad == 0) ? LD8G(th + (size_t)(q0 + wave * 16 + lr) * 8) : zf;

    f32x4 O[2];
    f32x4 l4;
#pragma unroll
    for (int r = 0; r < 4; ++r) { O[0][r] = 0.f; O[1][r] = 0.f; l4[r] = 0.f; }

    // per-lane phi byte voffsets (loop-invariant)
    const int voff_ph0 = (0 * 16 + lr) * 16;
    const int voff_ph1 = (1 * 16 + lr) * 16;
    const int voff_ph2 = (2 * 16 + lr) * 16;
    const int voff_ph3 = (3 * 16 + lr) * 16;

    s16x8 phB_e[4], phB_o[4];
    s16x8 greg_e, greg_o;

#define GL4(dst, off, base)                                                   \
    asm volatile("global_load_dwordx4 %0, %1, %2"                             \
                 : "=v"(dst) : "v"(off), "s"(base) : "memory")

#define LOADPH_A(dst, baseT)                                                  \
    GL4(dst[0], voff_ph0, baseT); GL4(dst[1], voff_ph1, baseT);               \
    GL4(dst[2], voff_ph2, baseT); GL4(dst[3], voff_ph3, baseT);

#define WAITVM(n) asm volatile("s_waitcnt vmcnt(" #n ")" ::: "memory")

#define QK(Sv, phB)                                                           \
    _Pragma("unroll")                                                         \
    for (int ss = 0; ss < 4; ++ss)                                            \
        Sv[ss] = __builtin_amdgcn_mfma_f32_16x16x32_bf16(thA, phB[ss], zc, 0, 0, 0);

#define EXPST(Sv, wbuf)                                                       \
    _Pragma("unroll")                                                         \
    for (int ss = 0; ss < 4; ++ss)                                            \
        _Pragma("unroll")                                                     \
        for (int r = 0; r < 4; ++r) {                                         \
            const float p = exp2f(Sv[ss][r]);                                 \
            l4[r] += p;                                                       \
            Pw[(wbuf) + (quad * 4 + r) * 72 + ss * 16 + lr] =                 \
                (unsigned short)(__float_as_uint(p) >> 16);                   \
        }

#define BODY(phCUR, phNXT, gCUR, gNXT, curT, LAST)                            \
    {                                                                         \
        WAITVM(4);   /* retire G chunk of st(curT) (oldest of 5) */           \
        __syncthreads();                                                      \
        *(s16x8*)(stg + ((curT) & 1) * 2048 + sch * 64 + swz * 8) = gCUR;     \
        if (!(LAST)) {                                                        \
            const int stn = ((curT) + 1 + stoff) & 15;                        \
            GL4(gNXT, voff_gc, gp + (size_t)stn * 64);                        \
            LOADPH_A(phNXT, ph + (size_t)stn * 512);                          \
        }                                                                     \
        const int pb = ((curT) - 1) & 1;                                      \
        const s16x8 Pf0 = *(const s16x8*)(Pw + pb * 1152 + lr * 72 + quad * 8);      \
        const s16x8 Pf1 = *(const s16x8*)(Pw + pb * 1152 + lr * 72 + 32 + quad * 8); \
        s16x8 Gf[2][2];                                                       \
        _Pragma("unroll")                                                     \
        for (int kc = 0; kc < 2; ++kc)                                        \
            _Pragma("unroll")                                                 \
            for (int cs = 0; cs < 2; ++cs)                                    \
                Gf[kc][cs] = *(const s16x8*)(stg + pb * 2048 +                \
                    (cs * 16 + lr) * 64 + ((kc * 4 + quad) ^ (lr & 7)) * 8);  \
        if (LAST) { WAITVM(0); } else { WAITVM(5); }  /* phi(st(curT)) */     \
        SB();                                                                 \
        f32x4 S[4];                                                           \
        QK(S, phCUR);                                                         \
        _Pragma("unroll")                                                     \
        for (int cs = 0; cs < 2; ++cs)                                        \
            O[cs] = __builtin_amdgcn_mfma_f32_16x16x32_bf16(Pf0, Gf[0][cs], O[cs], 0, 0, 0); \
        _Pragma("unroll")                                                     \
        for (int cs = 0; cs < 2; ++cs)                                        \
            O[cs] = __builtin_amdgcn_mfma_f32_16x16x32_bf16(Pf1, Gf[1][cs], O[cs], 0, 0, 0); \
        EXPST(S, ((curT) & 1) * 1152);                                        \
    }

    // ---- prologue: tile st(0) ----
    {
        const int st0 = stoff;
        const int st1 = (stoff + 1) & 15;
        GL4(greg_e, voff_gc, gp + (size_t)st0 * 64);
        LOADPH_A(phB_e, ph + (size_t)st0 * 512);
        WAITVM(4);                              // retire G(st0)
        *(s16x8*)(stg + 0 * 2048 + sch * 64 + swz * 8) = greg_e;
        GL4(greg_o, voff_gc, gp + (size_t)st1 * 64);
        LOADPH_A(phB_o, ph + (size_t)st1 * 512);
        WAITVM(5);                              // retire phi(st0)
        SB();
        f32x4 S[4];
        QK(S, phB_e);
        EXPST(S, 0);
    }

    // ---- steady state: t = 1..14 in ping-pong pairs ----
    for (int t = 1; t < 15; t += 2) {
        BODY(phB_o, phB_e, greg_o, greg_e, t,     0);
        BODY(phB_e, phB_o, greg_e, greg_o, t + 1, 0);
    }
    // ---- t = 15 (no next prefetch) ----
    BODY(phB_o, phB_e, greg_o, greg_e, 15, 1);

    // ---- drain: PV for tile st(15) (P in buf1, G in stage[1]) ----
    {
        __syncthreads();                        // stage[1] written by all
        const s16x8 Pf0 = *(const s16x8*)(Pw + 1152 + lr * 72 + quad * 8);
        const s16x8 Pf1 = *(const s16x8*)(Pw + 1152 + lr * 72 + 32 + quad * 8);
        s16x8 Gf[2][2];
#pragma unroll
        for (int kc = 0; kc < 2; ++kc)
#pragma unroll
            for (int cs = 0; cs < 2; ++cs)
                Gf[kc][cs] = *(const s16x8*)(stg + 2048 +
                    (cs * 16 + lr) * 64 + ((kc * 4 + quad) ^ (lr & 7)) * 8);
#pragma unroll
        for (int cs = 0; cs < 2; ++cs)
            O[cs] = __builtin_amdgcn_mfma_f32_16x16x32_bf16(Pf0, Gf[0][cs], O[cs], 0, 0, 0);
#pragma unroll
        for (int cs = 0; cs < 2; ++cs)
            O[cs] = __builtin_amdgcn_mfma_f32_16x16x32_bf16(Pf1, Gf[1][cs], O[cs], 0, 0, 0);
    }

    // l: butterfly-sum over the 16-lane s-groups
#pragma unroll
    for (int r = 0; r < 4; ++r) {
        float v = l4[r];
        v += __shfl_xor(v, 1);
        v += __shfl_xor(v, 2);
        v += __shfl_xor(v, 4);
        v += __shfl_xor(v, 8);
        l4[r] = 1.f / v;
    }

    __syncthreads();                          // all waves done with Pw/stage
    float* otile = (float*)smem;              // [32 c][68 q-stride]
#pragma unroll
    for (int cs = 0; cs < 2; ++cs) {
        f32x4 v;
#pragma unroll
        for (int r = 0; r < 4; ++r) v[r] = O[cs][r] * l4[r];
        *(f32x4*)(otile + (cs * 16 + lr) * 68 + wave * 16 + quad * 4) = v;
    }
    __syncthreads();

    // Wo epilogue + residual: thread = (q = tid&63, oc quarter = tid>>6)
    const int qq = tid & 63;
    const int quarter = __builtin_amdgcn_readfirstlane(tid >> 6);
    float ov[32];
#pragma unroll
    for (int c = 0; c < 32; ++c) ov[c] = otile[c * 68 + qq];
    const float gam = gamma_p[0];
#pragma unroll
    for (int j = 0; j < 16; ++j) {
        const float* wrow = Wo + (size_t)(quarter * 16 + j) * 32;  // contiguous
        float a = 0.f;
#pragma unroll
        for (int c = 0; c < 32; ++c) a += wrow[c] * ov[c];         // s_load
        const size_t ad = ((size_t)b * NC + quarter * 16 + j) * HWs + q0 + qq;
        out[ad] = gam * a + x[ad];
    }
}

extern "C" void kernel_launch(void* const* d_in, const int* in_sizes, int n_in,
                              void* d_out, int out_size, void* d_ws, size_t ws_size,
                              hipStream_t stream) {
    const float* x     = (const float*)d_in[0];
    const float* Wt    = (const float*)d_in[1];
    const float* Wp    = (const float*)d_in[2];
    const float* Wg    = (const float*)d_in[3];
    const float* Wo    = (const float*)d_in[4];
    const float* gamma = (const float*)d_in[5];
    float* out = (float*)d_out;
    unsigned short* ws = (unsigned short*)d_ws;

    k_proj<<<2048, 256, 0, stream>>>(x, Wt, Wp, Wg, ws);
    k_attn<<<1024, 256, 0, stream>>>(x, Wo, gamma, ws, out);
}

// Round 13
// 127.105 us; speedup vs baseline: 1.0316x; 1.0316x over previous
//
#include <hip/hip_runtime.h>
#include <math.h>

// Problem constants
#define NB   16
#define NC   64
#define HWs  4096
#define NPS  1024
#define LOG2E 1.44269504088896341f

// ws layout in ushort (bf16 bit patterns)
static constexpr size_t PHI_OFF = (size_t)NB * HWs * 8;            // theta: [b][4096][8]
static constexpr size_t GT_OFF  = PHI_OFF + (size_t)NB * NPS * 8;  // phi:   [b][1024][8]
// gT: [b][32][1024]; total 1,179,648 ushorts = 2.25 MB
static constexpr size_t PROBE_OFF = (size_t)16 * 1024 * 1024;      // 32 MB scratch for probe

typedef short s16x8 __attribute__((ext_vector_type(8)));
typedef float f32x4 __attribute__((ext_vector_type(4)));

#define LD8G(p) (*(const s16x8*)(p))
#define SB()    __builtin_amdgcn_sched_barrier(0)

__device__ inline unsigned short f2bf(float f) {
    unsigned int u = __float_as_uint(f);
    u += 0x7fffu + ((u >> 16) & 1u);          // RNE
    return (unsigned short)(u >> 16);
}
__device__ inline unsigned int pk2(float a, float b) {
    unsigned int ua = __float_as_uint(a); ua += 0x7fffu + ((ua >> 16) & 1u);
    unsigned int ub = __float_as_uint(b); ub += 0x7fffu + ((ub >> 16) & 1u);
    return (ua >> 16) | (ub & 0xffff0000u);
}

// ---------------------------------------------------------------------------
// proj body (v5, the best-measured config: 112.0 us total in round 10).
// Round-17 post-mortem: BOTH alternative weight paths regressed proj by
// ~18 us (v6 readlane: +VALU & hazards; v7 LDS-staged: +19 us, mechanism
// still unconfirmed) -> v5's s_load loop is reinstated byte-equivalent, and
// this body is shared by the real kernel and an instrumentation probe so
// the probe measures EXACTLY this code.
// ---------------------------------------------------------------------------
__device__ __forceinline__ void proj_body(
    const float* __restrict__ x, const float* __restrict__ Wt,
    const float* __restrict__ Wp, const float* __restrict__ Wg,
    unsigned short* __restrict__ theta, unsigned short* __restrict__ phi,
    unsigned short* __restrict__ gT, int blk, int tid)
{
    __shared__ float xs[64 * 64];             // 16 KB

    const int b    = blk >> 7;
    const int rp   = (blk >> 2) & 31;         // image rows {2rp, 2rp+1}
    const int half = (blk >> 1) & 1;          // block-uniform -> SGPR
    const int csub = blk & 1;                 // column half (32 cols)
    const int col0 = csub * 32;

    // ---- stage x[b][ci][rows 2rp,2rp+1][cols col0..col0+32) -> xs[ci][64] ----
    const float* xsrc = x + (size_t)b * NC * HWs + rp * 128;
#pragma unroll
    for (int i = 0; i < 4; ++i) {
        const int idx  = i * 256 + tid;       // 0..1023 float4 slots
        const int ci   = idx >> 4;
        const int slot = idx & 15;
        const int r    = slot >> 3;
        const int c4   = slot & 7;
        float4 v = *(const float4*)(xsrc + (size_t)ci * HWs + r * 64 + col0 + c4 * 4);
        *(float4*)(xs + ci * 64 + r * 32 + c4 * 4) = v;
    }
    __syncthreads();

    const int pxl = tid & 63;                 // r = pxl>>5, c = pxl&31
    const int r   = pxl >> 5;
    const int c   = pxl & 31;
    const int grp = __builtin_amdgcn_readfirstlane(tid >> 6);   // 0..3, SGPR

    float a2[2], ag4[4];
#pragma unroll
    for (int j = 0; j < 2; ++j) a2[j] = 0.f;
#pragma unroll
    for (int j = 0; j < 4; ++j) ag4[j] = 0.f;

    const float* W8 = (half ? Wp : Wt) + grp * 2 * NC;           // scalar base
    const float* WG = Wg + (half * 16 + grp * 4) * NC;           // scalar base

#pragma unroll 8
    for (int ci = 0; ci < NC; ++ci) {
        const float xv = xs[ci * 64 + pxl];   // 2-way bank alias: free
#pragma unroll
        for (int j = 0; j < 2; ++j) a2[j] += W8[j * NC + ci] * xv;    // s_load
#pragma unroll
        for (int j = 0; j < 4; ++j) ag4[j] += WG[j * NC + ci] * xv;   // s_load
    }

    if (half == 0) {
        // theta: unpooled, scaled by log2e; channels grp*2 .. grp*2+2
        const int q = (2 * rp + r) * 64 + col0 + c;
        *(unsigned int*)(theta + ((size_t)b * HWs + q) * 8 + grp * 2) =
            pk2(a2[0] * LOG2E, a2[1] * LOG2E);
    } else {
        // phi pooling: row pair (xor 32), col pair (xor 1)
#pragma unroll
        for (int j = 0; j < 2; ++j) {
            float v = a2[j];
            v = fmaxf(v, __shfl_xor(v, 32));
            v = fmaxf(v, __shfl_xor(v, 1));
            a2[j] = v;
        }
    }

    // g pooling (both halves)
#pragma unroll
    for (int j = 0; j < 4; ++j) {
        float v = ag4[j];
        v = fmaxf(v, __shfl_xor(v, 32));
        v = fmaxf(v, __shfl_xor(v, 1));
        ag4[j] = v;
    }

    if (r == 0 && (c & 1) == 0) {
        const int ps = rp * 32 + csub * 16 + (c >> 1);
        if (half == 1) {
            *(unsigned int*)(phi + ((size_t)b * NPS + ps) * 8 + grp * 2) =
                pk2(a2[0], a2[1]);
        }
#pragma unroll
        for (int j = 0; j < 4; ++j) {
            const int ch = half * 16 + grp * 4 + j;
            gT[((size_t)b * 32 + ch) * NPS + ps] = f2bf(ag4[j]);
        }
    }
}

__global__ __launch_bounds__(256) __attribute__((amdgpu_waves_per_eu(8, 8)))
void k_proj(
    const float* __restrict__ x, const float* __restrict__ Wt,
    const float* __restrict__ Wp, const float* __restrict__ Wg,
    unsigned short* __restrict__ ws)
{
    proj_body(x, Wt, Wp, Wg, ws, ws + PHI_OFF, ws + GT_OFF,
              blockIdx.x, threadIdx.x);
}

// ---------------------------------------------------------------------------
// INSTRUMENTATION PROBE (round 17): proj has NEVER had counters (always
// below the top-5 cutoff; 4 rounds of totals-only inference produced two
// falsified theories). Probe = identical body, 2x grid (blk & 2047), output
// to ws+32MB scratch (live region is 2.25MB; fill poisons 268MB so the
// scratch exists and is dead). ~56 us > ~45 us fills -> top-5 row #1 with
// VALUBusy/Occupancy/FETCH/LDS-conflict for EXACTLY the v5 code.
// Decision tree: VALU>=55% issue-bound | VALU<=40%+Occ>=60% latency-chain |
// bank-conflicts high -> xs layout | FETCH>>64MB -> L2 locality.
// ---------------------------------------------------------------------------
__global__ __launch_bounds__(256) __attribute__((amdgpu_waves_per_eu(8, 8)))
void k_proj_probe(
    const float* __restrict__ x, const float* __restrict__ Wt,
    const float* __restrict__ Wp, const float* __restrict__ Wg,
    unsigned short* __restrict__ ws)
{
    unsigned short* base = ws + PROBE_OFF;
    proj_body(x, Wt, Wp, Wg, base, base + PHI_OFF, base + GT_OFF,
              blockIdx.x & 2047, threadIdx.x);
}

// ---------------------------------------------------------------------------
// Kernel 2 (v11): L2-dedup + tile stagger. UNCHANGED (best-known attn,
// ~34 us by totals).
// (1) G-tile (4 KB) staged ONCE per block via asm loads + XOR-swizzled
// ds_write; PV reads frags via swizzled ds_read_b128. One __syncthreads per
// tile = the cross-wave hand-off. (2) Stagger tile order st=(t+blk&15)&15 —
// legal: non-online softmax, tile order is permutation-invariant.
// vmcnt ledger: 5 loads/body; vmcnt(4) before ds_write, vmcnt(5) before QK,
// body-15 waits 0. LDS: P 18432 + stage 8192 = 26624 B.
// ---------------------------------------------------------------------------
__global__ __launch_bounds__(256) __attribute__((amdgpu_waves_per_eu(4, 4)))
void k_attn(
    const float* __restrict__ x, const float* __restrict__ Wo,
    const float* __restrict__ gamma_p, const unsigned short* __restrict__ ws,
    float* __restrict__ out)
{
    __shared__ __align__(16) unsigned char smem[26624];

    const int tid  = threadIdx.x;
    const int wave = __builtin_amdgcn_readfirstlane(tid >> 6);
    const int lane = tid & 63;
    const int quad = lane >> 4, lr = lane & 15;
    const int blk  = blockIdx.x;
    const int b    = blk >> 6;
    const int q0   = (blk & 63) * 64;
    const int stoff = blk & 15;               // tile stagger (block-uniform)

    const unsigned short* th = ws + (size_t)b * HWs * 8;
    const unsigned short* ph = ws + PHI_OFF + (size_t)b * NPS * 8;
    const unsigned short* gp = ws + GT_OFF + (size_t)b * 32 * NPS;
    unsigned short* Pw  = (unsigned short*)smem + wave * 2304;     // 2 bufs x [16 q][72 s]
    unsigned short* stg = (unsigned short*)(smem + 18432);         // 2 bufs x [32 ch][64 s]

    // G staging map: thread -> one 16B chunk (ch = tid>>3, part = tid&7),
    // XOR-swizzled column so frag reads spread across banks.
    const int sch   = tid >> 3;
    const int spart = tid & 7;
    const int swz   = spart ^ (sch & 7);
    const int voff_gc = sch * (NPS * 2) + spart * 16;   // byte voffset into gT slab

    const s16x8 zf = {0, 0, 0, 0, 0, 0, 0, 0};
    const f32x4 zc = {0.f, 0.f, 0.f, 0.f};

    // theta A-fragment: A[m=q=lr][k=quad*8+j], real k<8 in quad 0
    const s16x8 thA = (quad == 0) ? LD8G(th + (size_t)(q0 + wave * 16 + lr) * 8) : zf;

    f32x4 O[2];
    f32x4 l4;
#pragma unroll
    for (int r = 0; r < 4; ++r) { O[0][r] = 0.f; O[1][r] = 0.f; l4[r] = 0.f; }

    // per-lane phi byte voffsets (loop-invariant)
    const int voff_ph0 = (0 * 16 + lr) * 16;
    const int voff_ph1 = (1 * 16 + lr) * 16;
    const int voff_ph2 = (2 * 16 + lr) * 16;
    const int voff_ph3 = (3 * 16 + lr) * 16;

    s16x8 phB_e[4], phB_o[4];
    s16x8 greg_e, greg_o;

#define GL4(dst, off, base)                                                   \
    asm volatile("global_load_dwordx4 %0, %1, %2"                             \
                 : "=v"(dst) : "v"(off), "s"(base) : "memory")

#define LOADPH_A(dst, baseT)                                                  \
    GL4(dst[0], voff_ph0, baseT); GL4(dst[1], voff_ph1, baseT);               \
    GL4(dst[2], voff_ph2, baseT); GL4(dst[3], voff_ph3, baseT);

#define WAITVM(n) asm volatile("s_waitcnt vmcnt(" #n ")" ::: "memory")

#define QK(Sv, phB)                                                           \
    _Pragma("unroll")                                                         \
    for (int ss = 0; ss < 4; ++ss)                                            \
        Sv[ss] = __builtin_amdgcn_mfma_f32_16x16x32_bf16(thA, phB[ss], zc, 0, 0, 0);

#define EXPST(Sv, wbuf)                                                       \
    _Pragma("unroll")                                                         \
    for (int ss = 0; ss < 4; ++ss)                                            \
        _Pragma("unroll")                                                     \
        for (int r = 0; r < 4; ++r) {                                         \
            const float p = exp2f(Sv[ss][r]);                                 \
            l4[r] += p;                                                       \
            Pw[(wbuf) + (quad * 4 + r) * 72 + ss * 16 + lr] =                 \
                (unsigned short)(__float_as_uint(p) >> 16);                   \
        }

#define BODY(phCUR, phNXT, gCUR, gNXT, curT, LAST)                            \
    {                                                                         \
        WAITVM(4);   /* retire G chunk of st(curT) (oldest of 5) */           \
        __syncthreads();                                                      \
        *(s16x8*)(stg + ((curT) & 1) * 2048 + sch * 64 + swz * 8) = gCUR;     \
        if (!(LAST)) {                                                        \
            const int stn = ((curT) + 1 + stoff) & 15;                        \
            GL4(gNXT, voff_gc, gp + (size_t)stn * 64);                        \
            LOADPH_A(phNXT, ph + (size_t)stn * 512);                          \
        }                                                                     \
        const int pb = ((curT) - 1) & 1;                                      \
        const s16x8 Pf0 = *(const s16x8*)(Pw + pb * 1152 + lr * 72 + quad * 8);      \
        const s16x8 Pf1 = *(const s16x8*)(Pw + pb * 1152 + lr * 72 + 32 + quad * 8); \
        s16x8 Gf[2][2];                                                       \
        _Pragma("unroll")                                                     \
        for (int kc = 0; kc < 2; ++kc)                                        \
            _Pragma("unroll")                                                 \
            for (int cs = 0; cs < 2; ++cs)                                    \
                Gf[kc][cs] = *(const s16x8*)(stg + pb * 2048 +                \
                    (cs * 16 + lr) * 64 + ((kc * 4 + quad) ^ (lr & 7)) * 8);  \
        if (LAST) { WAITVM(0); } else { WAITVM(5); }  /* phi(st(curT)) */     \
        SB();                                                                 \
        f32x4 S[4];                                                           \
        QK(S, phCUR);                                                         \
        _Pragma("unroll")                                                     \
        for (int cs = 0; cs < 2; ++cs)                                        \
            O[cs] = __builtin_amdgcn_mfma_f32_16x16x32_bf16(Pf0, Gf[0][cs], O[cs], 0, 0, 0); \
        _Pragma("unroll")                                                     \
        for (int cs = 0; cs < 2; ++cs)                                        \
            O[cs] = __builtin_amdgcn_mfma_f32_16x16x32_bf16(Pf1, Gf[1][cs], O[cs], 0, 0, 0); \
        EXPST(S, ((curT) & 1) * 1152);                                        \
    }

    // ---- prologue: tile st(0) ----
    {
        const int st0 = stoff;
        const int st1 = (stoff + 1) & 15;
        GL4(greg_e, voff_gc, gp + (size_t)st0 * 64);
        LOADPH_A(phB_e, ph + (size_t)st0 * 512);
        WAITVM(4);                              // retire G(st0)
        *(s16x8*)(stg + 0 * 2048 + sch * 64 + swz * 8) = greg_e;
        GL4(greg_o, voff_gc, gp + (size_t)st1 * 64);
        LOADPH_A(phB_o, ph + (size_t)st1 * 512);
        WAITVM(5);                              // retire phi(st0)
        SB();
        f32x4 S[4];
        QK(S, phB_e);
        EXPST(S, 0);
    }

    // ---- steady state: t = 1..14 in ping-pong pairs ----
    for (int t = 1; t < 15; t += 2) {
        BODY(phB_o, phB_e, greg_o, greg_e, t,     0);
        BODY(phB_e, phB_o, greg_e, greg_o, t + 1, 0);
    }
    // ---- t = 15 (no next prefetch) ----
    BODY(phB_o, phB_e, greg_o, greg_e, 15, 1);

    // ---- drain: PV for tile st(15) (P in buf1, G in stage[1]) ----
    {
        __syncthreads();                        // stage[1] written by all
        const s16x8 Pf0 = *(const s16x8*)(Pw + 1152 + lr * 72 + quad * 8);
        const s16x8 Pf1 = *(const s16x8*)(Pw + 1152 + lr * 72 + 32 + quad * 8);
        s16x8 Gf[2][2];
#pragma unroll
        for (int kc = 0; kc < 2; ++kc)
#pragma unroll
            for (int cs = 0; cs < 2; ++cs)
                Gf[kc][cs] = *(const s16x8*)(stg + 2048 +
                    (cs * 16 + lr) * 64 + ((kc * 4 + quad) ^ (lr & 7)) * 8);
#pragma unroll
        for (int cs = 0; cs < 2; ++cs)
            O[cs] = __builtin_amdgcn_mfma_f32_16x16x32_bf16(Pf0, Gf[0][cs], O[cs], 0, 0, 0);
#pragma unroll
        for (int cs = 0; cs < 2; ++cs)
            O[cs] = __builtin_amdgcn_mfma_f32_16x16x32_bf16(Pf1, Gf[1][cs], O[cs], 0, 0, 0);
    }

    // l: butterfly-sum over the 16-lane s-groups
#pragma unroll
    for (int r = 0; r < 4; ++r) {
        float v = l4[r];
        v += __shfl_xor(v, 1);
        v += __shfl_xor(v, 2);
        v += __shfl_xor(v, 4);
        v += __shfl_xor(v, 8);
        l4[r] = 1.f / v;
    }

    __syncthreads();                          // all waves done with Pw/stage
    float* otile = (float*)smem;              // [32 c][68 q-stride]
#pragma unroll
    for (int cs = 0; cs < 2; ++cs) {
        f32x4 v;
#pragma unroll
        for (int r = 0; r < 4; ++r) v[r] = O[cs][r] * l4[r];
        *(f32x4*)(otile + (cs * 16 + lr) * 68 + wave * 16 + quad * 4) = v;
    }
    __syncthreads();

    // Wo epilogue + residual: thread = (q = tid&63, oc quarter = tid>>6)
    const int qq = tid & 63;
    const int quarter = __builtin_amdgcn_readfirstlane(tid >> 6);
    float ov[32];
#pragma unroll
    for (int c = 0; c < 32; ++c) ov[c] = otile[c * 68 + qq];
    const float gam = gamma_p[0];
#pragma unroll
    for (int j = 0; j < 16; ++j) {
        const float* wrow = Wo + (size_t)(quarter * 16 + j) * 32;  // contiguous
        float a = 0.f;
#pragma unroll
        for (int c = 0; c < 32; ++c) a += wrow[c] * ov[c];         // s_load
        const size_t ad = ((size_t)b * NC + quarter * 16 + j) * HWs + q0 + qq;
        out[ad] = gam * a + x[ad];
    }
}

extern "C" void kernel_launch(void* const* d_in, const int* in_sizes, int n_in,
                              void* d_out, int out_size, void* d_ws, size_t ws_size,
                              hipStream_t stream) {
    const float* x     = (const float*)d_in[0];
    const float* Wt    = (const float*)d_in[1];
    const float* Wp    = (const float*)d_in[2];
    const float* Wg    = (const float*)d_in[3];
    const float* Wo    = (const float*)d_in[4];
    const float* gamma = (const float*)d_in[5];
    float* out = (float*)d_out;
    unsigned short* ws = (unsigned short*)d_ws;

    // Probe first (cold caches, representative); writes only to ws+32MB scratch.
    k_proj_probe<<<4096, 256, 0, stream>>>(x, Wt, Wp, Wg, ws);
    k_proj<<<2048, 256, 0, stream>>>(x, Wt, Wp, Wg, ws);
    k_attn<<<1024, 256, 0, stream>>>(x, Wo, gamma, ws, out);
}